// Round 10
// baseline (166.160 us; speedup 1.0000x reference)
//
#include <hip/hip_runtime.h>
#include <hip/hip_bf16.h>

typedef float v4f __attribute__((ext_vector_type(4)));
typedef float f32x4 __attribute__((ext_vector_type(4)));
typedef unsigned short u16;
typedef unsigned short us4 __attribute__((ext_vector_type(4)));
typedef unsigned short us8 __attribute__((ext_vector_type(8)));
typedef short s16x8 __attribute__((ext_vector_type(8)));

#define N_NODES 10000
#define N_EDGES 160000

// XOR-swizzle on ushort index: spreads stride-128B rows across bank quads.
#define SWZ(idx, row) ((idx) ^ (((row) & 7) << 3))

__device__ __forceinline__ u16 f2b(float x) {
  union { float f; unsigned u; } v; v.f = x;
  unsigned r = v.u + 0x7fffu + ((v.u >> 16) & 1u);
  return (u16)(r >> 16);
}
__device__ __forceinline__ float b2f(u16 u) {
  union { unsigned u; float f; } v; v.u = ((unsigned)u) << 16; return v.f;
}
__device__ __forceinline__ float silu_f(float x) { return x / (1.0f + __expf(-x)); }

// lgkm-only barrier: keeps global (vmcnt) loads in flight across it.
__device__ __forceinline__ void bar_lgkm() {
  asm volatile("s_waitcnt lgkmcnt(0)" ::: "memory");
  __builtin_amdgcn_s_barrier();
}

// ---------------- prep: pack weight A-fragments (lane-major, bf16) ----------
// fid = frag*64 + lane; lane holds A[ut*16 + (lane&15)][kbase + (lane>>4)*8 + j].
// Sections (fids): L2 @0 (512), L3 @512, L4 @1024 (1024), NS @2048 (1024),
// NV @3072 (1024), L1 @4096 (256, K=8 zero-padded to 32). Zeroes out[4n].
__global__ __launch_bounds__(256) void prep_kernel(
    const float* __restrict__ fcw0,
    const float* __restrict__ fcw1, const float* __restrict__ fcw2,
    const float* __restrict__ fcw3,
    const float* __restrict__ W10, const float* __restrict__ W20,
    const float* __restrict__ W11, const float* __restrict__ W21,
    u16* __restrict__ prep, float* __restrict__ out)
{
  const int fid = blockIdx.x * 256 + threadIdx.x;   // 0..4351
  for (int i = fid; i < N_NODES; i += 4352) out[(size_t)i * 4] = 0.f;
  int f, sec;
  if (fid < 512)       { sec = 0; f = fid; }
  else if (fid < 1024) { sec = 1; f = fid - 512; }
  else if (fid < 2048) { sec = 2; f = fid - 1024; }
  else if (fid < 3072) { sec = 3; f = fid - 2048; }
  else if (fid < 4096) { sec = 4; f = fid - 3072; }
  else                 { sec = 5; f = fid - 4096; }
  const int lane = f & 63;
  us8 vals;
  if (sec == 5) {
    const int ut = f >> 6;
    #pragma unroll
    for (int j = 0; j < 8; ++j) {
      const int k = (lane >> 4) * 8 + j;
      vals[j] = (k < 8) ? f2b(fcw0[k * 64 + ut * 16 + (lane & 15)]) : (u16)0;
    }
  } else {
    const int kw = (f >> 6) & 1, ut = f >> 7;
    #pragma unroll
    for (int j = 0; j < 8; ++j) {
      const int k = kw * 32 + (lane >> 4) * 8 + j;
      float v;
      if (sec == 0) v = fcw1[k * 64 + ut * 16 + (lane & 15)];
      else if (sec == 1) v = fcw2[k * 64 + ut * 16 + (lane & 15)];
      else if (sec == 2) {
        const int col = (ut < 4) ? (ut * 16 + (lane & 15)) : (192 + (ut - 4) * 16 + (lane & 15));
        v = fcw3[k * 256 + col];
      } else if (sec == 3) {
        const int u = ut * 16 + (lane & 15);
        v = (u < 64) ? W10[k * 64 + u] : W20[k * 64 + (u - 64)];
      } else {
        const int u = ut * 16 + (lane & 15);
        v = (u < 64) ? W11[k * 64 + u] : W21[k * 64 + (u - 64)];
      }
      vals[j] = f2b(v);
    }
  }
  *(us8*)&prep[(size_t)fid * 8] = vals;
}

// ---------------- node kernel: 16 nodes/block, 625 blocks -------------------
// Atab[n][256] = [s1 | v1x | v1y | v1z] bf16 (x0.125 folded); Btab: s2,v2.
__global__ __launch_bounds__(256) void node_kernel(
    const float* __restrict__ nf,
    const u16* __restrict__ prepNS, const u16* __restrict__ prepNV,
    const float* __restrict__ Wm1,
    u16* __restrict__ Atab, u16* __restrict__ Btab, float* __restrict__ out)
{
  __shared__ u16 Ss[1024];
  __shared__ u16 Vs[3][1024];
  __shared__ float wm1s[64];
  const int tid = threadIdx.x, w = tid >> 6, lane = tid & 63;
  const int nb = blockIdx.x;

  if (tid < 64) wm1s[tid] = Wm1[tid];
  #pragma unroll
  for (int it = 0; it < 4; ++it) {
    const int flat = it * 1024 + tid * 4;
    const int nl = flat >> 8;            // 0..15
    const int col = flat & 255;
    const v4f x = *(const v4f*)&nf[((size_t)(nb * 16 + nl)) * 256 + col];
    #pragma unroll
    for (int i = 0; i < 4; ++i) {
      const int c2 = col + i;
      const u16 b = f2b(x[i]);
      if (c2 < 64) Ss[SWZ(nl * 64 + c2, nl)] = b;
      else {
        const int cc = c2 - 64, c = cc / 3, m = cc - c * 3;
        Vs[m][SWZ(nl * 64 + c, nl)] = b;
      }
    }
  }
  __syncthreads();

  const int nr = lane & 15, kg = (lane >> 4) * 8;
  const u16* plane = (w == 0) ? Ss : Vs[w - 1];   // wave = pass (s,x,y,z)
  const u16* pw = (w == 0) ? prepNS : prepNV;
  const s16x8 b0 = *(const s16x8*)&plane[SWZ(nr * 64 + kg, nr)];
  const s16x8 b1 = *(const s16x8*)&plane[SWZ(nr * 64 + 32 + kg, nr)];
  const int node = nb * 16 + nr;
  #pragma unroll
  for (int utg = 0; utg < 8; ++utg) {
    const s16x8 a0 = *(const s16x8*)&pw[((utg * 2 + 0) * 64 + lane) * 8];
    const s16x8 a1 = *(const s16x8*)&pw[((utg * 2 + 1) * 64 + lane) * 8];
    f32x4 acc = {0.f, 0.f, 0.f, 0.f};
    acc = __builtin_amdgcn_mfma_f32_16x16x32_bf16(a0, b0, acc, 0, 0, 0);
    acc = __builtin_amdgcn_mfma_f32_16x16x32_bf16(a1, b1, acc, 0, 0, 0);
    us4 st;
    #pragma unroll
    for (int j = 0; j < 4; ++j) st[j] = f2b(acc[j] * 0.125f);
    u16* tab = (utg < 4) ? Atab : Btab;
    const int ch = w * 64 + (utg & 3) * 16 + (lane >> 4) * 4;
    *(us4*)&tab[(size_t)node * 256 + ch] = st;
  }

  // mvec: 192 threads, 4 per (node,m) task, shuffle-combine
  if (tid < 192) {
    const int task = tid >> 2, sub = tid & 3;
    const int nl3 = task / 3, m = task - nl3 * 3;
    float acc = 0.f;
    #pragma unroll
    for (int i = 0; i < 16; ++i) {
      const int c = sub * 16 + i;
      acc += b2f(Vs[m][SWZ(nl3 * 64 + c, nl3)]) * wm1s[c];
    }
    acc += __shfl_xor(acc, 1);
    acc += __shfl_xor(acc, 2);
    if (sub == 0) out[(nb * 16 + nl3) * 4 + 1 + m] = acc * 0.125f;
  }
}

// layer (32 edges): Hin -> Hout (swizzled [edge][k] bf16), A-frags in VGPRs
__device__ __forceinline__ void mfma_layer32(const u16* Hin, u16* Hout,
                                             s16x8 a0, s16x8 a1, int w, int lane) {
  const int er = lane & 15, kg = (lane >> 4) * 8;
  __builtin_amdgcn_s_setprio(1);
  #pragma unroll
  for (int et = 0; et < 2; ++et) {
    const int e = et * 16 + er;
    const s16x8 b0 = *(const s16x8*)&Hin[SWZ(e * 64 + kg, e)];
    const s16x8 b1 = *(const s16x8*)&Hin[SWZ(e * 64 + 32 + kg, e)];
    f32x4 acc = {0.f, 0.f, 0.f, 0.f};
    acc = __builtin_amdgcn_mfma_f32_16x16x32_bf16(a0, b0, acc, 0, 0, 0);
    acc = __builtin_amdgcn_mfma_f32_16x16x32_bf16(a1, b1, acc, 0, 0, 0);
    us4 st;
    #pragma unroll
    for (int j = 0; j < 4; ++j) st[j] = f2b(silu_f(acc[j] * 0.125f));
    *(us4*)&Hout[SWZ(e * 64 + w * 16 + (lane >> 4) * 4, e)] = st;
  }
  __builtin_amdgcn_s_setprio(0);
}

// ---------------- edge kernel: 4-tile pipeline, register gathers ------------
// 1250 blocks x 4 tiles of 32 edges. Gathers(t) issue at tile-top into lane
// registers (each lane gathers exactly the 8B chunks its contraction uses);
// vmcnt(0) after L4, no gather barrier. Indices pipelined one tile ahead.
__global__ __launch_bounds__(256, 2) void edge_kernel(
    const float* __restrict__ edge_attrs,
    const float* __restrict__ edge_feats,
    const int*   __restrict__ edge_index,
    const u16*   __restrict__ prep,     // L2 @0, L3 @512*8, L4 @1024*8, L1 @4096*8
    const float* __restrict__ Wf,
    const u16*   __restrict__ Atab, const u16* __restrict__ Btab,
    float* __restrict__ out, float* __restrict__ p_out)
{
  __shared__ u16 HA[2048], HB[2048];   // activations [e][k], swizzled
  __shared__ u16 F16[256];             // [e][k] 32x8 bf16 edge feats
  __shared__ float yL[4][32];
  __shared__ float Psum[128];          // [wave][edge]

  const int tid = threadIdx.x, w = tid >> 6, lane = tid & 63;
  const int er = lane & 15, kg = (lane >> 4) * 8;
  const int cb = w * 16 + (lane >> 4) * 4;   // channel base (4 ch)
  const int eb0 = blockIdx.x * 128;          // 4 tiles x 32 edges

  // ---- persistent weights (once per block) ----
  const u16* pL2 = prep;
  const u16* pL3 = prep + 512 * 8;
  const u16* pL4 = prep + 1024 * 8;
  const s16x8 a2_0 = *(const s16x8*)&pL2[((w * 2 + 0) * 64 + lane) * 8];
  const s16x8 a2_1 = *(const s16x8*)&pL2[((w * 2 + 1) * 64 + lane) * 8];
  const s16x8 a3_0 = *(const s16x8*)&pL3[((w * 2 + 0) * 64 + lane) * 8];
  const s16x8 a3_1 = *(const s16x8*)&pL3[((w * 2 + 1) * 64 + lane) * 8];
  const s16x8 as0 = *(const s16x8*)&pL4[((w * 2 + 0) * 64 + lane) * 8];
  const s16x8 as1 = *(const s16x8*)&pL4[((w * 2 + 1) * 64 + lane) * 8];
  const s16x8 av0 = *(const s16x8*)&pL4[(((4 + w) * 2 + 0) * 64 + lane) * 8];
  const s16x8 av1 = *(const s16x8*)&pL4[(((4 + w) * 2 + 1) * 64 + lane) * 8];
  const s16x8 a1w = *(const s16x8*)&prep[(size_t)(4096 + w * 64 + lane) * 8];
  const v4f wfA = *(const v4f*)&Wf[cb];
  v4f wfB = *(const v4f*)&Wf[64 + cb];
  #pragma unroll
  for (int j = 0; j < 4; ++j) wfB[j] *= 0.5773502691896258f;

  // cross-tile register state
  int sndv[2][2], rcvv[2][2];          // [buf][et] gather row indices (per-lane)
  int sndR[2], rcvR[2];                // epilogue (tid<32)
  v4f eaR, f0R, f1R;                   // single-buffered staging
  us4 gA[2][4], gB[2][4];              // [et][sec] gather data (single buffer)

  // ---- prologue: idx(0) + staging(0) ----
  {
    #pragma unroll
    for (int et = 0; et < 2; ++et) {
      sndv[0][et] = edge_index[eb0 + et * 16 + er];
      rcvv[0][et] = edge_index[N_EDGES + eb0 + et * 16 + er];
    }
    if (tid < 32) {
      sndR[0] = edge_index[eb0 + tid];
      rcvR[0] = edge_index[N_EDGES + eb0 + tid];
      eaR = *(const v4f*)&edge_attrs[(size_t)(eb0 + tid) * 4];
      f0R = *(const v4f*)&edge_feats[(size_t)(eb0 + tid) * 8];
      f1R = *(const v4f*)&edge_feats[(size_t)(eb0 + tid) * 8 + 4];
      yL[0][tid] = eaR[0]; yL[1][tid] = eaR[1];
      yL[2][tid] = eaR[2]; yL[3][tid] = eaR[3];
      us8 o;
      #pragma unroll
      for (int k = 0; k < 4; ++k) { o[k] = f2b(f0R[k]); o[4 + k] = f2b(f1R[k]); }
      *(us8*)&F16[tid * 8] = o;
    }
    bar_lgkm();
  }

  #pragma unroll
  for (int t = 0; t < 4; ++t) {
    const int cur = t & 1, nxt = cur ^ 1;
    const int eb = eb0 + t * 32;

    // (1) issue gathers(t): per-lane 16x 8B from A/B tables (land during MLP)
    #pragma unroll
    for (int et = 0; et < 2; ++et) {
      const u16* ra = Atab + (size_t)sndv[cur][et] * 256 + cb;
      const u16* rb = Btab + (size_t)rcvv[cur][et] * 256 + cb;
      #pragma unroll
      for (int sec = 0; sec < 4; ++sec) {
        gA[et][sec] = *(const us4*)&ra[sec * 64];
        gB[et][sec] = *(const us4*)&rb[sec * 64];
      }
    }
    __builtin_amdgcn_sched_barrier(0);   // pin gather issue point

    // (2) issue idx(t+1) + staging(t+1)
    if (t < 3) {
      const int ebn = eb + 32;
      #pragma unroll
      for (int et = 0; et < 2; ++et) {
        sndv[nxt][et] = edge_index[ebn + et * 16 + er];
        rcvv[nxt][et] = edge_index[N_EDGES + ebn + et * 16 + er];
      }
      if (tid < 32) {
        sndR[nxt] = edge_index[ebn + tid];
        rcvR[nxt] = edge_index[N_EDGES + ebn + tid];
        eaR = *(const v4f*)&edge_attrs[(size_t)(ebn + tid) * 4];
        f0R = *(const v4f*)&edge_feats[(size_t)(ebn + tid) * 8];
        f1R = *(const v4f*)&edge_feats[(size_t)(ebn + tid) * 8 + 4];
      }
      __builtin_amdgcn_sched_barrier(0);
    }

    // (3) layer 1 via MFMA: K=8 padded to 32; lanes>=16 supply zero B
    {
      __builtin_amdgcn_s_setprio(1);
      #pragma unroll
      for (int et = 0; et < 2; ++et) {
        s16x8 bF = {0, 0, 0, 0, 0, 0, 0, 0};
        if (lane < 16) bF = *(const s16x8*)&F16[(et * 16 + lane) * 8];
        f32x4 acc = {0.f, 0.f, 0.f, 0.f};
        acc = __builtin_amdgcn_mfma_f32_16x16x32_bf16(a1w, bF, acc, 0, 0, 0);
        const int e = et * 16 + er;
        us4 st;
        #pragma unroll
        for (int j = 0; j < 4; ++j)
          st[j] = f2b(silu_f(acc[j] * 0.35355339059327373f));
        *(us4*)&HA[SWZ(e * 64 + w * 16 + (lane >> 4) * 4, e)] = st;
      }
      __builtin_amdgcn_s_setprio(0);
    }
    bar_lgkm();
    mfma_layer32(HA, HB, a2_0, a2_1, w, lane);   // layer 2
    bar_lgkm();
    mfma_layer32(HB, HA, a3_0, a3_1, w, lane);   // layer 3
    bar_lgkm();

    // (4) layer 4 (MFMA) into registers
    f32x4 accS[2], accV[2];
    __builtin_amdgcn_s_setprio(1);
    #pragma unroll
    for (int et = 0; et < 2; ++et) {
      const int e = et * 16 + er;
      const s16x8 b0 = *(const s16x8*)&HA[SWZ(e * 64 + kg, e)];
      const s16x8 b1 = *(const s16x8*)&HA[SWZ(e * 64 + 32 + kg, e)];
      f32x4 aS = {0.f,0.f,0.f,0.f}, aV = {0.f,0.f,0.f,0.f};
      aS = __builtin_amdgcn_mfma_f32_16x16x32_bf16(as0, b0, aS, 0, 0, 0);
      aS = __builtin_amdgcn_mfma_f32_16x16x32_bf16(as1, b1, aS, 0, 0, 0);
      aV = __builtin_amdgcn_mfma_f32_16x16x32_bf16(av0, b0, aV, 0, 0, 0);
      aV = __builtin_amdgcn_mfma_f32_16x16x32_bf16(av1, b1, aV, 0, 0, 0);
      accS[et] = aS; accV[et] = aV;
    }
    __builtin_amdgcn_s_setprio(0);

    // (5) own gathers + idx/staging landed (per-wave wait, no barrier)
    asm volatile("s_waitcnt vmcnt(0)" ::: "memory");

    // (6) contraction from registers
    #pragma unroll
    for (int et = 0; et < 2; ++et) {
      const int e = et * 16 + er;
      const float y0 = yL[0][e], yx = yL[1][e], yy = yL[2][e], yz = yL[3][e];
      float part = 0.f;
      #pragma unroll
      for (int j = 0; j < 4; ++j) {
        const float bs = b2f(gA[et][0][j]) + b2f(gB[et][0][j]);
        const float bv = (b2f(gA[et][1][j]) + b2f(gB[et][1][j])) * yx +
                         (b2f(gA[et][2][j]) + b2f(gB[et][2][j])) * yy +
                         (b2f(gA[et][3][j]) + b2f(gB[et][3][j])) * yz;
        part += accS[et][j] * bs * y0 * wfA[j] + accV[et][j] * bv * wfB[j];
      }
      part += __shfl_xor(part, 16);
      part += __shfl_xor(part, 32);
      if (lane < 16) Psum[w * 32 + et * 16 + lane] = part;
    }
    bar_lgkm();

    // (7) epilogue + stage next tile's F16 / y
    if (tid < 32) {
      // fold: 0.125 (layer-4 1/sqrt(64)) / sqrt(128) / 40
      const float p = (Psum[tid] + Psum[32 + tid] + Psum[64 + tid] + Psum[96 + tid])
                      * 2.7621358640766505e-4f;
      p_out[eb + tid] = p;
      atomicAdd(&out[(size_t)rcvR[cur] * 4], p);
      atomicAdd(&out[(size_t)sndR[cur] * 4], -p);
      if (t < 3) {
        yL[0][tid] = eaR[0]; yL[1][tid] = eaR[1];
        yL[2][tid] = eaR[2]; yL[3][tid] = eaR[3];
        us8 o;
        #pragma unroll
        for (int k = 0; k < 4; ++k) { o[k] = f2b(f0R[k]); o[4 + k] = f2b(f1R[k]); }
        *(us8*)&F16[tid * 8] = o;
      }
    }
    bar_lgkm();
  }
}

extern "C" void kernel_launch(void* const* d_in, const int* in_sizes, int n_in,
                              void* d_out, int out_size, void* d_ws, size_t ws_size,
                              hipStream_t stream) {
  const float* node_feats = (const float*)d_in[1];
  const float* edge_attrs = (const float*)d_in[2];
  const float* edge_feats = (const float*)d_in[3];
  const int*   edge_index = (const int*)d_in[4];
  const float* W10  = (const float*)d_in[8];
  const float* W11  = (const float*)d_in[9];
  const float* W20  = (const float*)d_in[10];
  const float* W21  = (const float*)d_in[11];
  const float* fcw0 = (const float*)d_in[12];
  const float* fcw1 = (const float*)d_in[13];
  const float* fcw2 = (const float*)d_in[14];
  const float* fcw3 = (const float*)d_in[15];
  const float* Wf   = (const float*)d_in[16];
  const float* Wm1  = (const float*)d_in[17];
  float* out = (float*)d_out;

  char* ws = (char*)d_ws;
  u16* Atab = (u16*)ws;                              // 10000*256 u16
  u16* Btab = (u16*)(ws + 5120000);
  u16* prep = (u16*)(ws + 10240000);                 // 4352 frag-rows * 16B

  prep_kernel<<<17, 256, 0, stream>>>(fcw0, fcw1, fcw2, fcw3, W10, W20, W11, W21,
                                      prep, out);
  node_kernel<<<625, 256, 0, stream>>>(node_feats, prep + 2048 * 8, prep + 3072 * 8,
                                       Wm1, Atab, Btab, out);
  edge_kernel<<<1250, 256, 0, stream>>>(edge_attrs, edge_feats, edge_index,
                                        prep, Wf, Atab, Btab,
                                        out, out + 40000);
}

// Round 12
// 145.486 us; speedup vs baseline: 1.1421x; 1.1421x over previous
//
#include <hip/hip_runtime.h>
#include <hip/hip_bf16.h>

typedef float v4f __attribute__((ext_vector_type(4)));
typedef float f32x4 __attribute__((ext_vector_type(4)));
typedef unsigned short u16;
typedef unsigned short us4 __attribute__((ext_vector_type(4)));
typedef unsigned short us8 __attribute__((ext_vector_type(8)));
typedef short s16x8 __attribute__((ext_vector_type(8)));

#define N_NODES 10000
#define N_EDGES 160000
#define NTILE 8

// XOR-swizzle on ushort index: spreads stride-128B rows across bank quads.
#define SWZ(idx, row) ((idx) ^ (((row) & 7) << 3))
// Gather-buffer read index: row r (512B = 32 x 16B granules), u16 offset o;
// granule XOR'd with row&7 (matches pre-swizzled global source of the glds).
#define GIDX(r, o) (((r) << 8) + (((((o) >> 3) ^ ((r) & 7))) << 3) + ((o) & 7))

__device__ __forceinline__ u16 f2b(float x) {
  union { float f; unsigned u; } v; v.f = x;
  unsigned r = v.u + 0x7fffu + ((v.u >> 16) & 1u);
  return (u16)(r >> 16);
}
__device__ __forceinline__ float b2f(u16 u) {
  union { unsigned u; float f; } v; v.u = ((unsigned)u) << 16; return v.f;
}
__device__ __forceinline__ float silu_f(float x) { return x / (1.0f + __expf(-x)); }

// lgkm-only barrier: keeps global (vmcnt) loads/glds in flight across it.
__device__ __forceinline__ void bar_lgkm() {
  asm volatile("s_waitcnt lgkmcnt(0)" ::: "memory");
  __builtin_amdgcn_s_barrier();
}

// async gather: 16B from per-lane global addr -> LDS base + lane*16
__device__ __forceinline__ void gload_lds16(const u16* g, u16* l) {
  __builtin_amdgcn_global_load_lds(
      (const __attribute__((address_space(1))) unsigned int*)g,
      (__attribute__((address_space(3))) unsigned int*)l, 16, 0, 0);
}

// ---------------- prep: pack weight A-fragments (lane-major, bf16) ----------
// fid = frag*64 + lane; lane holds A[ut*16 + (lane&15)][kbase + (lane>>4)*8 + j].
// Sections (fids): L2 @0 (512), L3 @512, L4 @1024 (1024), NS @2048 (1024),
// NV @3072 (1024), L1 @4096 (256, K=8 zero-padded to 32). Zeroes out[4n].
__global__ __launch_bounds__(256) void prep_kernel(
    const float* __restrict__ fcw0,
    const float* __restrict__ fcw1, const float* __restrict__ fcw2,
    const float* __restrict__ fcw3,
    const float* __restrict__ W10, const float* __restrict__ W20,
    const float* __restrict__ W11, const float* __restrict__ W21,
    u16* __restrict__ prep, float* __restrict__ out)
{
  const int fid = blockIdx.x * 256 + threadIdx.x;   // 0..4351
  for (int i = fid; i < N_NODES; i += 4352) out[(size_t)i * 4] = 0.f;
  int f, sec;
  if (fid < 512)       { sec = 0; f = fid; }
  else if (fid < 1024) { sec = 1; f = fid - 512; }
  else if (fid < 2048) { sec = 2; f = fid - 1024; }
  else if (fid < 3072) { sec = 3; f = fid - 2048; }
  else if (fid < 4096) { sec = 4; f = fid - 3072; }
  else                 { sec = 5; f = fid - 4096; }
  const int lane = f & 63;
  us8 vals;
  if (sec == 5) {
    const int ut = f >> 6;
    #pragma unroll
    for (int j = 0; j < 8; ++j) {
      const int k = (lane >> 4) * 8 + j;
      vals[j] = (k < 8) ? f2b(fcw0[k * 64 + ut * 16 + (lane & 15)]) : (u16)0;
    }
  } else {
    const int kw = (f >> 6) & 1, ut = f >> 7;
    #pragma unroll
    for (int j = 0; j < 8; ++j) {
      const int k = kw * 32 + (lane >> 4) * 8 + j;
      float v;
      if (sec == 0) v = fcw1[k * 64 + ut * 16 + (lane & 15)];
      else if (sec == 1) v = fcw2[k * 64 + ut * 16 + (lane & 15)];
      else if (sec == 2) {
        const int col = (ut < 4) ? (ut * 16 + (lane & 15)) : (192 + (ut - 4) * 16 + (lane & 15));
        v = fcw3[k * 256 + col];
      } else if (sec == 3) {
        const int u = ut * 16 + (lane & 15);
        v = (u < 64) ? W10[k * 64 + u] : W20[k * 64 + (u - 64)];
      } else {
        const int u = ut * 16 + (lane & 15);
        v = (u < 64) ? W11[k * 64 + u] : W21[k * 64 + (u - 64)];
      }
      vals[j] = f2b(v);
    }
  }
  *(us8*)&prep[(size_t)fid * 8] = vals;
}

// ---------------- node kernel: 16 nodes/block, 625 blocks -------------------
// Atab[n][256] = [s1 | v1x | v1y | v1z] bf16 (x0.125 folded); Btab: s2,v2.
__global__ __launch_bounds__(256) void node_kernel(
    const float* __restrict__ nf,
    const u16* __restrict__ prepNS, const u16* __restrict__ prepNV,
    const float* __restrict__ Wm1,
    u16* __restrict__ Atab, u16* __restrict__ Btab, float* __restrict__ out)
{
  __shared__ u16 Ss[1024];
  __shared__ u16 Vs[3][1024];
  __shared__ float wm1s[64];
  const int tid = threadIdx.x, w = tid >> 6, lane = tid & 63;
  const int nb = blockIdx.x;

  if (tid < 64) wm1s[tid] = Wm1[tid];
  #pragma unroll
  for (int it = 0; it < 4; ++it) {
    const int flat = it * 1024 + tid * 4;
    const int nl = flat >> 8;            // 0..15
    const int col = flat & 255;
    const v4f x = *(const v4f*)&nf[((size_t)(nb * 16 + nl)) * 256 + col];
    #pragma unroll
    for (int i = 0; i < 4; ++i) {
      const int c2 = col + i;
      const u16 b = f2b(x[i]);
      if (c2 < 64) Ss[SWZ(nl * 64 + c2, nl)] = b;
      else {
        const int cc = c2 - 64, c = cc / 3, m = cc - c * 3;
        Vs[m][SWZ(nl * 64 + c, nl)] = b;
      }
    }
  }
  __syncthreads();

  const int nr = lane & 15, kg = (lane >> 4) * 8;
  const u16* plane = (w == 0) ? Ss : Vs[w - 1];   // wave = pass (s,x,y,z)
  const u16* pw = (w == 0) ? prepNS : prepNV;
  const s16x8 b0 = *(const s16x8*)&plane[SWZ(nr * 64 + kg, nr)];
  const s16x8 b1 = *(const s16x8*)&plane[SWZ(nr * 64 + 32 + kg, nr)];
  const int node = nb * 16 + nr;
  #pragma unroll
  for (int utg = 0; utg < 8; ++utg) {
    const s16x8 a0 = *(const s16x8*)&pw[((utg * 2 + 0) * 64 + lane) * 8];
    const s16x8 a1 = *(const s16x8*)&pw[((utg * 2 + 1) * 64 + lane) * 8];
    f32x4 acc = {0.f, 0.f, 0.f, 0.f};
    acc = __builtin_amdgcn_mfma_f32_16x16x32_bf16(a0, b0, acc, 0, 0, 0);
    acc = __builtin_amdgcn_mfma_f32_16x16x32_bf16(a1, b1, acc, 0, 0, 0);
    us4 st;
    #pragma unroll
    for (int j = 0; j < 4; ++j) st[j] = f2b(acc[j] * 0.125f);
    u16* tab = (utg < 4) ? Atab : Btab;
    const int ch = w * 64 + (utg & 3) * 16 + (lane >> 4) * 4;
    *(us4*)&tab[(size_t)node * 256 + ch] = st;
  }

  // mvec: 192 threads, 4 per (node,m) task, shuffle-combine
  if (tid < 192) {
    const int task = tid >> 2, sub = tid & 3;
    const int nl3 = task / 3, m = task - nl3 * 3;
    float acc = 0.f;
    #pragma unroll
    for (int i = 0; i < 16; ++i) {
      const int c = sub * 16 + i;
      acc += b2f(Vs[m][SWZ(nl3 * 64 + c, nl3)]) * wm1s[c];
    }
    acc += __shfl_xor(acc, 1);
    acc += __shfl_xor(acc, 2);
    if (sub == 0) out[(nb * 16 + nl3) * 4 + 1 + m] = acc * 0.125f;
  }
}

// layer (32 edges): Hin -> Hout (swizzled [edge][k] bf16), A-frags in VGPRs
__device__ __forceinline__ void mfma_layer32(const u16* Hin, u16* Hout,
                                             s16x8 a0, s16x8 a1, int w, int lane) {
  const int er = lane & 15, kg = (lane >> 4) * 8;
  __builtin_amdgcn_s_setprio(1);
  #pragma unroll
  for (int et = 0; et < 2; ++et) {
    const int e = et * 16 + er;
    const s16x8 b0 = *(const s16x8*)&Hin[SWZ(e * 64 + kg, e)];
    const s16x8 b1 = *(const s16x8*)&Hin[SWZ(e * 64 + 32 + kg, e)];
    f32x4 acc = {0.f, 0.f, 0.f, 0.f};
    acc = __builtin_amdgcn_mfma_f32_16x16x32_bf16(a0, b0, acc, 0, 0, 0);
    acc = __builtin_amdgcn_mfma_f32_16x16x32_bf16(a1, b1, acc, 0, 0, 0);
    us4 st;
    #pragma unroll
    for (int j = 0; j < 4; ++j) st[j] = f2b(silu_f(acc[j] * 0.125f));
    *(us4*)&Hout[SWZ(e * 64 + w * 16 + (lane >> 4) * 4, e)] = st;
  }
  __builtin_amdgcn_s_setprio(0);
}

// ---------------- edge kernel: 8-tile pipeline, single-G, 3 blocks/CU -------
// 625 blocks x 8 tiles of 32 edges; all blocks co-resident (42.5 KB LDS).
// Gathers(t+1) issue after contraction(t) reads G (single buffer), then land
// during the whole MLP of tile t+1 (in flight across 2 barriers).
__global__ __launch_bounds__(256, 2) void edge_kernel(
    const float* __restrict__ edge_attrs,
    const float* __restrict__ edge_feats,
    const int*   __restrict__ edge_index,
    const u16*   __restrict__ prep,     // L2 @0, L3 @512*8, L4 @1024*8, L1 @4096*8
    const float* __restrict__ Wf,
    const u16*   __restrict__ Atab, const u16* __restrict__ Btab,
    float* __restrict__ out, float* __restrict__ p_out)
{
  __shared__ u16 G[16384];             // 32 KB gather buffer (single)
  __shared__ u16 HA[2048], HB[2048];   // activations [e][k], swizzled
  __shared__ u16 F16[256];             // [e][k] 32x8 bf16 edge feats
  __shared__ float yL[4][32];
  __shared__ float Psum[128];          // [wave][edge]

  const int tid = threadIdx.x, w = tid >> 6, lane = tid & 63;
  const int half = lane >> 5, l31 = lane & 31;
  const int er = lane & 15, kg = (lane >> 4) * 8;
  const int cb = w * 16 + (lane >> 4) * 4;   // channel base (4 ch)
  const int eb0 = blockIdx.x * (NTILE * 32);

  // ---- persistent weights (once per block) ----
  const u16* pL2 = prep;
  const u16* pL3 = prep + 512 * 8;
  const u16* pL4 = prep + 1024 * 8;
  const s16x8 a2_0 = *(const s16x8*)&pL2[((w * 2 + 0) * 64 + lane) * 8];
  const s16x8 a2_1 = *(const s16x8*)&pL2[((w * 2 + 1) * 64 + lane) * 8];
  const s16x8 a3_0 = *(const s16x8*)&pL3[((w * 2 + 0) * 64 + lane) * 8];
  const s16x8 a3_1 = *(const s16x8*)&pL3[((w * 2 + 1) * 64 + lane) * 8];
  const s16x8 as0 = *(const s16x8*)&pL4[((w * 2 + 0) * 64 + lane) * 8];
  const s16x8 as1 = *(const s16x8*)&pL4[((w * 2 + 1) * 64 + lane) * 8];
  const s16x8 av0 = *(const s16x8*)&pL4[(((4 + w) * 2 + 0) * 64 + lane) * 8];
  const s16x8 av1 = *(const s16x8*)&pL4[(((4 + w) * 2 + 1) * 64 + lane) * 8];
  const s16x8 a1w = *(const s16x8*)&prep[(size_t)(4096 + w * 64 + lane) * 8];
  const v4f wfA = *(const v4f*)&Wf[cb];
  v4f wfB = *(const v4f*)&Wf[64 + cb];
  #pragma unroll
  for (int j = 0; j < 4; ++j) wfB[j] *= 0.5773502691896258f;

  const u16* tabW = (w < 2) ? Atab : Btab;          // this wave gathers A or B
  const int  eoff = (w < 2) ? 0 : N_EDGES;

  // cross-tile register state
  int nidx[2][8];                      // [buf][i] gather row node indices
  int sndR[2], rcvR[2];                // epilogue (tid<32)
  v4f eaR, f0R, f1R;                   // single-buffered staging regs

  // ---- prologue: tile 0 ----
  {
    #pragma unroll
    for (int i = 0; i < 8; ++i)
      nidx[0][i] = edge_index[eoff + eb0 + (w & 1) * 16 + 2 * i + half];
    if (tid < 32) {
      sndR[0] = edge_index[eb0 + tid];
      rcvR[0] = edge_index[N_EDGES + eb0 + tid];
      eaR = *(const v4f*)&edge_attrs[(size_t)(eb0 + tid) * 4];
      f0R = *(const v4f*)&edge_feats[(size_t)(eb0 + tid) * 8];
      f1R = *(const v4f*)&edge_feats[(size_t)(eb0 + tid) * 8 + 4];
    }
    asm volatile("s_waitcnt vmcnt(0)" ::: "memory");
    #pragma unroll
    for (int i = 0; i < 8; ++i) {
      const int grow = w * 16 + 2 * i + half;
      const u16* src = tabW + (size_t)nidx[0][i] * 256 + (size_t)((l31 ^ (grow & 7)) << 3);
      gload_lds16(src, &G[(w * 16 + 2 * i) * 256]);
    }
    __builtin_amdgcn_sched_barrier(0);
    if (tid < 32) {
      yL[0][tid] = eaR[0]; yL[1][tid] = eaR[1];
      yL[2][tid] = eaR[2]; yL[3][tid] = eaR[3];
      us8 o;
      #pragma unroll
      for (int k = 0; k < 4; ++k) { o[k] = f2b(f0R[k]); o[4 + k] = f2b(f1R[k]); }
      *(us8*)&F16[tid * 8] = o;
    }
    bar_lgkm();
  }

  #pragma unroll
  for (int t = 0; t < NTILE; ++t) {
    const int cur = t & 1, nxt = cur ^ 1;
    const int eb = eb0 + t * 32;

    // (1) issue next tile's index + staging loads (land before this vmcnt(0))
    if (t < NTILE - 1) {
      const int ebn = eb + 32;
      #pragma unroll
      for (int i = 0; i < 8; ++i)
        nidx[nxt][i] = edge_index[eoff + ebn + (w & 1) * 16 + 2 * i + half];
      if (tid < 32) {
        sndR[nxt] = edge_index[ebn + tid];
        rcvR[nxt] = edge_index[N_EDGES + ebn + tid];
        eaR = *(const v4f*)&edge_attrs[(size_t)(ebn + tid) * 4];
        f0R = *(const v4f*)&edge_feats[(size_t)(ebn + tid) * 8];
        f1R = *(const v4f*)&edge_feats[(size_t)(ebn + tid) * 8 + 4];
      }
      __builtin_amdgcn_sched_barrier(0);   // pin issue point
    }

    // (2) layer 1 via MFMA: K=8 padded to 32; lanes>=16 supply zero B
    {
      __builtin_amdgcn_s_setprio(1);
      #pragma unroll
      for (int et = 0; et < 2; ++et) {
        s16x8 bF = {0, 0, 0, 0, 0, 0, 0, 0};
        if (lane < 16) bF = *(const s16x8*)&F16[(et * 16 + lane) * 8];
        f32x4 acc = {0.f, 0.f, 0.f, 0.f};
        acc = __builtin_amdgcn_mfma_f32_16x16x32_bf16(a1w, bF, acc, 0, 0, 0);
        const int e = et * 16 + er;
        us4 st;
        #pragma unroll
        for (int j = 0; j < 4; ++j)
          st[j] = f2b(silu_f(acc[j] * 0.35355339059327373f));
        *(us4*)&HA[SWZ(e * 64 + w * 16 + (lane >> 4) * 4, e)] = st;
      }
      __builtin_amdgcn_s_setprio(0);
    }
    bar_lgkm();
    mfma_layer32(HA, HB, a2_0, a2_1, w, lane);   // layer 2
    bar_lgkm();
    mfma_layer32(HB, HA, a3_0, a3_1, w, lane);   // layer 3
    bar_lgkm();

    // (3) layer 4 (MFMA) into registers
    f32x4 accS[2], accV[2];
    __builtin_amdgcn_s_setprio(1);
    #pragma unroll
    for (int et = 0; et < 2; ++et) {
      const int e = et * 16 + er;
      const s16x8 b0 = *(const s16x8*)&HA[SWZ(e * 64 + kg, e)];
      const s16x8 b1 = *(const s16x8*)&HA[SWZ(e * 64 + 32 + kg, e)];
      f32x4 aS = {0.f,0.f,0.f,0.f}, aV = {0.f,0.f,0.f,0.f};
      aS = __builtin_amdgcn_mfma_f32_16x16x32_bf16(as0, b0, aS, 0, 0, 0);
      aS = __builtin_amdgcn_mfma_f32_16x16x32_bf16(as1, b1, aS, 0, 0, 0);
      aV = __builtin_amdgcn_mfma_f32_16x16x32_bf16(av0, b0, aV, 0, 0, 0);
      aV = __builtin_amdgcn_mfma_f32_16x16x32_bf16(av1, b1, aV, 0, 0, 0);
      accS[et] = aS; accV[et] = aV;
    }
    __builtin_amdgcn_s_setprio(0);

    // (4) gathers(t) + idx/staging(t+1) landed; sync all waves
    asm volatile("s_waitcnt vmcnt(0)" ::: "memory");
    __builtin_amdgcn_s_barrier();

    // (5) contraction from G
    #pragma unroll
    for (int et = 0; et < 2; ++et) {
      const int e = et * 16 + er;
      const int rA = e, rB = 32 + e;
      const us4 As = *(const us4*)&G[GIDX(rA, cb)];
      const us4 Ax = *(const us4*)&G[GIDX(rA, 64 + cb)];
      const us4 Ay = *(const us4*)&G[GIDX(rA, 128 + cb)];
      const us4 Az = *(const us4*)&G[GIDX(rA, 192 + cb)];
      const us4 Bs = *(const us4*)&G[GIDX(rB, cb)];
      const us4 Bx = *(const us4*)&G[GIDX(rB, 64 + cb)];
      const us4 By = *(const us4*)&G[GIDX(rB, 128 + cb)];
      const us4 Bz = *(const us4*)&G[GIDX(rB, 192 + cb)];
      const float y0 = yL[0][e], yx = yL[1][e], yy = yL[2][e], yz = yL[3][e];
      float part = 0.f;
      #pragma unroll
      for (int j = 0; j < 4; ++j) {
        const float bs = b2f(As[j]) + b2f(Bs[j]);
        const float bv = (b2f(Ax[j]) + b2f(Bx[j])) * yx +
                         (b2f(Ay[j]) + b2f(By[j])) * yy +
                         (b2f(Az[j]) + b2f(Bz[j])) * yz;
        part += accS[et][j] * bs * y0 * wfA[j] + accV[et][j] * bv * wfB[j];
      }
      part += __shfl_xor(part, 16);
      part += __shfl_xor(part, 32);
      if (lane < 16) Psum[w * 32 + et * 16 + lane] = part;
    }
    bar_lgkm();   // all G reads + yL reads + Psum writes done

    // (6) issue gathers(t+1) into G (reads complete; land during next MLP)
    if (t < NTILE - 1) {
      #pragma unroll
      for (int i = 0; i < 8; ++i) {
        const int grow = w * 16 + 2 * i + half;
        const u16* src = tabW + (size_t)nidx[nxt][i] * 256 + (size_t)((l31 ^ (grow & 7)) << 3);
        gload_lds16(src, &G[(w * 16 + 2 * i) * 256]);
      }
      __builtin_amdgcn_sched_barrier(0);
    }

    // (7) epilogue + stage next tile's F16 / y
    if (tid < 32) {
      // fold: 0.125 (layer-4 1/sqrt(64)) / sqrt(128) / 40
      const float p = (Psum[tid] + Psum[32 + tid] + Psum[64 + tid] + Psum[96 + tid])
                      * 2.7621358640766505e-4f;
      p_out[eb + tid] = p;
      atomicAdd(&out[(size_t)rcvR[cur] * 4], p);
      atomicAdd(&out[(size_t)sndR[cur] * 4], -p);
      if (t < NTILE - 1) {
        yL[0][tid] = eaR[0]; yL[1][tid] = eaR[1];
        yL[2][tid] = eaR[2]; yL[3][tid] = eaR[3];
        us8 o;
        #pragma unroll
        for (int k = 0; k < 4; ++k) { o[k] = f2b(f0R[k]); o[4 + k] = f2b(f1R[k]); }
        *(us8*)&F16[tid * 8] = o;
      }
    }
    bar_lgkm();
  }
}

extern "C" void kernel_launch(void* const* d_in, const int* in_sizes, int n_in,
                              void* d_out, int out_size, void* d_ws, size_t ws_size,
                              hipStream_t stream) {
  const float* node_feats = (const float*)d_in[1];
  const float* edge_attrs = (const float*)d_in[2];
  const float* edge_feats = (const float*)d_in[3];
  const int*   edge_index = (const int*)d_in[4];
  const float* W10  = (const float*)d_in[8];
  const float* W11  = (const float*)d_in[9];
  const float* W20  = (const float*)d_in[10];
  const float* W21  = (const float*)d_in[11];
  const float* fcw0 = (const float*)d_in[12];
  const float* fcw1 = (const float*)d_in[13];
  const float* fcw2 = (const float*)d_in[14];
  const float* fcw3 = (const float*)d_in[15];
  const float* Wf   = (const float*)d_in[16];
  const float* Wm1  = (const float*)d_in[17];
  float* out = (float*)d_out;

  char* ws = (char*)d_ws;
  u16* Atab = (u16*)ws;                              // 10000*256 u16
  u16* Btab = (u16*)(ws + 5120000);
  u16* prep = (u16*)(ws + 10240000);                 // 4352 frag-rows * 16B

  prep_kernel<<<17, 256, 0, stream>>>(fcw0, fcw1, fcw2, fcw3, W10, W20, W11, W21,
                                      prep, out);
  node_kernel<<<625, 256, 0, stream>>>(node_feats, prep + 2048 * 8, prep + 3072 * 8,
                                       Wm1, Atab, Btab, out);
  edge_kernel<<<625, 256, 0, stream>>>(edge_attrs, edge_feats, edge_index,
                                       prep, Wf, Atab, Btab,
                                       out, out + 40000);
}